// Round 1
// baseline (256.730 us; speedup 1.0000x reference)
//
#include <hip/hip_runtime.h>
#include <math.h>

#define N  2048
#define NT 256
#define EPT (N / NT)   // 8 elements per thread

__device__ inline double wave_red(double v) {
#pragma unroll
    for (int o = 32; o > 0; o >>= 1) v += __shfl_down(v, o, 64);
    return v;
}

// One block per batch row b: soft-rank pred row b and target row b, then
// Pearson correlation of the two rank vectors -> ws[b].
__global__ __launch_bounds__(NT) void spearman_rank_kernel(
        const float* __restrict__ pred, const float* __restrict__ target,
        float* __restrict__ ws) {
    __shared__ float  sv[N];      // sorted values (descending)
    __shared__ int    si[N];      // original indices (argsort payload)
    __shared__ float  rank_p[N];
    __shared__ float  rank_t[N];
    __shared__ double bsum[N];    // PAVA block sums; later aliased as float* means
    __shared__ int    bcnt[N];    // PAVA block counts; later overwritten with starts
    __shared__ int    nbA[NT];
    __shared__ int    nf_sh;
    __shared__ double redA[4], redB[4], redC[4];
    __shared__ double mshare[2];

    const int tid = threadIdx.x;
    const int b   = blockIdx.x;

    for (int which = 0; which < 2; ++which) {
        const float* row = (which == 0 ? pred : target) + (size_t)b * N;
        float* rank = (which == 0 ? rank_p : rank_t);

        // load
        for (int i = tid; i < N; i += NT) { sv[i] = row[i]; si[i] = i; }
        __syncthreads();

        // bitonic sort, descending, with index payload
        for (int k = 2; k <= N; k <<= 1) {
            for (int j = k >> 1; j > 0; j >>= 1) {
                for (int i = tid; i < N; i += NT) {
                    int p = i ^ j;
                    if (p > i) {
                        float a = sv[i], c = sv[p];
                        bool up = ((i & k) == 0);
                        if ((a < c) == up) {   // descending comparator
                            sv[i] = c; sv[p] = a;
                            int t0 = si[i]; si[i] = si[p]; si[p] = t0;
                        }
                    }
                }
                __syncthreads();
            }
        }

        // phase 1: per-thread PAVA (non-increasing fit) on 8 contiguous elems
        // y[g] = s[g] - w[g], w = [N, N-1, ..., 1] -> w[g] = N - g
        {
            const int base = tid * EPT;
            int m = 0;
            for (int e = 0; e < EPT; ++e) {
                const int g = base + e;
                double s = (double)sv[g] - (double)(N - g);
                int q = 1;
                while (m > 0) {
                    double ps = bsum[base + m - 1];
                    int    pq = bcnt[base + m - 1];
                    // violation of non-increasing: prev mean < new mean
                    if (ps * (double)q < s * (double)pq) { s += ps; q += pq; --m; }
                    else break;
                }
                bsum[base + m] = s; bcnt[base + m] = q; ++m;
            }
            nbA[tid] = m;
        }
        __syncthreads();

        // phase 2: thread 0 merges the 256 chunk block-lists (in-place stack:
        // write index m <= read index cb+t always, element read to regs first)
        if (tid == 0) {
            int m = 0;
            for (int c = 0; c < NT; ++c) {
                const int cb = c * EPT;
                const int k  = nbA[c];
                for (int t = 0; t < k; ++t) {
                    double s = bsum[cb + t]; int q = bcnt[cb + t];
                    while (m > 0 && bsum[m - 1] * (double)q < s * (double)bcnt[m - 1]) {
                        s += bsum[m - 1]; q += bcnt[m - 1]; --m;
                    }
                    bsum[m] = s; bcnt[m] = q; ++m;
                }
            }
            // compact: bcnt[f] -> block start, low half of bsum -> float mean.
            // float write at byte 4f never clobbers unread double at byte 8f'.
            float* bmean = (float*)bsum;
            int st = 0;
            for (int f = 0; f < m; ++f) {
                int    c = bcnt[f];
                double s = bsum[f];
                bcnt[f]  = st;
                bmean[f] = (float)(s / (double)c);
                st += c;
            }
            nf_sh = m;
        }
        __syncthreads();

        // phase 3: expand block means (binary search) and scatter ranks
        {
            const int m = nf_sh;
            const float* bmean  = (const float*)bsum;
            const int*   bstart = bcnt;
            for (int i = tid; i < N; i += NT) {
                int lo = 0, hi = m - 1;
                while (lo < hi) {
                    int mid = (lo + hi + 1) >> 1;
                    if (bstart[mid] <= i) lo = mid; else hi = mid - 1;
                }
                rank[si[i]] = sv[i] - bmean[lo];
            }
        }
        __syncthreads();
    }

    // Pearson correlation of rank_p vs rank_t (two-pass, double accumulators)
    double sp = 0.0, st2 = 0.0;
    for (int i = tid; i < N; i += NT) { sp += (double)rank_p[i]; st2 += (double)rank_t[i]; }
    sp = wave_red(sp); st2 = wave_red(st2);
    const int w = tid >> 6, lane = tid & 63;
    if (lane == 0) { redA[w] = sp; redB[w] = st2; }
    __syncthreads();
    if (tid == 0) {
        mshare[0] = (redA[0] + redA[1] + redA[2] + redA[3]) / (double)N;
        mshare[1] = (redB[0] + redB[1] + redB[2] + redB[3]) / (double)N;
    }
    __syncthreads();
    const double mp = mshare[0], mt = mshare[1];
    double cv = 0.0, vp = 0.0, vt = 0.0;
    for (int i = tid; i < N; i += NT) {
        double a = (double)rank_p[i] - mp;
        double c = (double)rank_t[i] - mt;
        cv += a * c; vp += a * a; vt += c * c;
    }
    cv = wave_red(cv); vp = wave_red(vp); vt = wave_red(vt);
    if (lane == 0) { redA[w] = cv; redB[w] = vp; redC[w] = vt; }
    __syncthreads();
    if (tid == 0) {
        double cvs = redA[0] + redA[1] + redA[2] + redA[3];
        double vps = redB[0] + redB[1] + redB[2] + redB[3];
        double vts = redC[0] + redC[1] + redC[2] + redC[3];
        ws[b] = (float)(cvs / (sqrt(vps) * sqrt(vts) + 1e-8));
    }
}

__global__ void spearman_finalize(const float* __restrict__ ws,
                                  float* __restrict__ out, int B) {
    if (threadIdx.x == 0 && blockIdx.x == 0) {
        float s = 0.f;
        for (int i = 0; i < B; ++i) s += ws[i];
        out[0] = 1.0f - s / (float)B;
    }
}

extern "C" void kernel_launch(void* const* d_in, const int* in_sizes, int n_in,
                              void* d_out, int out_size, void* d_ws, size_t ws_size,
                              hipStream_t stream) {
    const float* pred   = (const float*)d_in[0];
    const float* target = (const float*)d_in[1];
    float* out = (float*)d_out;
    float* ws  = (float*)d_ws;
    const int B = in_sizes[0] / N;   // 8

    spearman_rank_kernel<<<B, NT, 0, stream>>>(pred, target, ws);
    spearman_finalize<<<1, 64, 0, stream>>>(ws, out, B);
}

// Round 2
// 84.931 us; speedup vs baseline: 3.0228x; 3.0228x over previous
//
#include <hip/hip_runtime.h>
#include <math.h>

#define N  2048
#define NT 1024
#define NC 1024        // phase-1 chunks (2 elements each)
#define LEVELS 10      // log2(NC) tree-merge levels
#define NW (NT / 64)   // waves per block

__device__ inline double wave_red(double v) {
#pragma unroll
    for (int o = 32; o > 0; o >>= 1) v += __shfl_down(v, o, 64);
    return v;
}

// One block per batch row b: soft-rank pred row b and target row b, then
// Pearson correlation of the two rank vectors -> ws[b].
__global__ __launch_bounds__(NT) void spearman_rank_kernel(
        const float* __restrict__ pred, const float* __restrict__ target,
        float* __restrict__ ws) {
    __shared__ float  sv[N];      // sorted values (descending)
    __shared__ int    si[N];      // original indices (argsort payload)
    __shared__ float  rank_p[N];
    __shared__ float  rank_t[N];
    __shared__ double bsum[N];    // PAVA block sums; later aliased as float* means
    __shared__ int    bcnt[N];    // PAVA block counts; later block starts
    __shared__ int    nb[NC];     // per-chunk (later per-merged-list) block counts
    __shared__ int    nf_sh;
    __shared__ double redA[NW], redB[NW], redC[NW];
    __shared__ double mshare[2];

    const int tid = threadIdx.x;
    const int b   = blockIdx.x;

    for (int which = 0; which < 2; ++which) {
        const float* row = (which == 0 ? pred : target) + (size_t)b * N;
        float* rank = (which == 0 ? rank_p : rank_t);

        // load
        for (int i = tid; i < N; i += NT) { sv[i] = row[i]; si[i] = i; }
        __syncthreads();

        // bitonic sort, descending, with index payload
        for (int k = 2; k <= N; k <<= 1) {
            for (int j = k >> 1; j > 0; j >>= 1) {
                for (int i = tid; i < N; i += NT) {
                    int p = i ^ j;
                    if (p > i) {
                        float a = sv[i], c = sv[p];
                        bool up = ((i & k) == 0);
                        if ((a < c) == up) {   // descending comparator
                            sv[i] = c; sv[p] = a;
                            int t0 = si[i]; si[i] = si[p]; si[p] = t0;
                        }
                    }
                }
                __syncthreads();
            }
        }

        // phase 1: trivial PAVA on chunks of 2 contiguous elements.
        // y[g] = s[g] - w[g], w[g] = N - g. Non-increasing fit: pool iff y0 < y1.
        {
            const int g = tid * 2;
            double y0 = (double)sv[g]     - (double)(N - g);
            double y1 = (double)sv[g + 1] - (double)(N - g - 1);
            if (y0 < y1) { bsum[g] = y0 + y1; bcnt[g] = 2; nb[tid] = 1; }
            else {
                bsum[g] = y0;     bcnt[g] = 1;
                bsum[g + 1] = y1; bcnt[g + 1] = 1;
                nb[tid] = 2;
            }
        }

        // phase 2: parallel tree merge of chunk block-lists. At level l, one
        // thread merges the list at chunk c (width W=2^l chunks) with the list
        // at chunk c+W, processing right blocks as pre-pooled units into the
        // left stack (in-place: write index into right region <= read index).
        for (int l = 0; l < LEVELS; ++l) {
            __syncthreads();
            const int pairs = NC >> (l + 1);
            if (tid < pairs) {
                const int W  = 1 << l;
                const int c  = tid << (l + 1);
                const int lb = c * 2;
                const int rb = (c + W) * 2;
                int m = nb[c];
                const int rn = nb[c + W];
                for (int t = 0; t < rn; ++t) {
                    double s = bsum[rb + t]; int q = bcnt[rb + t];
                    while (m > 0) {
                        double ps = bsum[lb + m - 1]; int pq = bcnt[lb + m - 1];
                        if (ps * (double)q < s * (double)pq) { s += ps; q += pq; --m; }
                        else break;
                    }
                    bsum[lb + m] = s; bcnt[lb + m] = q; ++m;
                }
                nb[c] = m;
            }
        }
        __syncthreads();

        // compact: bcnt[f] -> block start, low half of bsum -> float mean.
        if (tid == 0) {
            const int m = nb[0];
            float* bmean = (float*)bsum;
            int st = 0;
            for (int f = 0; f < m; ++f) {
                int    c = bcnt[f];
                double s = bsum[f];
                bcnt[f]  = st;
                bmean[f] = (float)(s / (double)c);
                st += c;
            }
            nf_sh = m;
        }
        __syncthreads();

        // phase 3: expand block means (binary search) and scatter ranks
        {
            const int m = nf_sh;
            const float* bmean  = (const float*)bsum;
            const int*   bstart = bcnt;
            for (int i = tid; i < N; i += NT) {
                int lo = 0, hi = m - 1;
                while (lo < hi) {
                    int mid = (lo + hi + 1) >> 1;
                    if (bstart[mid] <= i) lo = mid; else hi = mid - 1;
                }
                rank[si[i]] = sv[i] - bmean[lo];
            }
        }
        __syncthreads();
    }

    // Pearson correlation of rank_p vs rank_t (two-pass, double accumulators)
    double sp = 0.0, st2 = 0.0;
    for (int i = tid; i < N; i += NT) { sp += (double)rank_p[i]; st2 += (double)rank_t[i]; }
    sp = wave_red(sp); st2 = wave_red(st2);
    const int w = tid >> 6, lane = tid & 63;
    if (lane == 0) { redA[w] = sp; redB[w] = st2; }
    __syncthreads();
    if (tid == 0) {
        double a = 0.0, c = 0.0;
        for (int i = 0; i < NW; ++i) { a += redA[i]; c += redB[i]; }
        mshare[0] = a / (double)N;
        mshare[1] = c / (double)N;
    }
    __syncthreads();
    const double mp = mshare[0], mt = mshare[1];
    double cv = 0.0, vp = 0.0, vt = 0.0;
    for (int i = tid; i < N; i += NT) {
        double a = (double)rank_p[i] - mp;
        double c = (double)rank_t[i] - mt;
        cv += a * c; vp += a * a; vt += c * c;
    }
    cv = wave_red(cv); vp = wave_red(vp); vt = wave_red(vt);
    if (lane == 0) { redA[w] = cv; redB[w] = vp; redC[w] = vt; }
    __syncthreads();
    if (tid == 0) {
        double cvs = 0.0, vps = 0.0, vts = 0.0;
        for (int i = 0; i < NW; ++i) { cvs += redA[i]; vps += redB[i]; vts += redC[i]; }
        ws[b] = (float)(cvs / (sqrt(vps) * sqrt(vts) + 1e-8));
    }
}

__global__ void spearman_finalize(const float* __restrict__ ws,
                                  float* __restrict__ out, int B) {
    if (threadIdx.x == 0 && blockIdx.x == 0) {
        float s = 0.f;
        for (int i = 0; i < B; ++i) s += ws[i];
        out[0] = 1.0f - s / (float)B;
    }
}

extern "C" void kernel_launch(void* const* d_in, const int* in_sizes, int n_in,
                              void* d_out, int out_size, void* d_ws, size_t ws_size,
                              hipStream_t stream) {
    const float* pred   = (const float*)d_in[0];
    const float* target = (const float*)d_in[1];
    float* out = (float*)d_out;
    float* ws  = (float*)d_ws;
    const int B = in_sizes[0] / N;   // 8

    spearman_rank_kernel<<<B, NT, 0, stream>>>(pred, target, ws);
    spearman_finalize<<<1, 64, 0, stream>>>(ws, out, B);
}

// Round 3
// 47.025 us; speedup vs baseline: 5.4595x; 1.8061x over previous
//
#include <hip/hip_runtime.h>
#include <math.h>

#define N    2048
#define NT   1024
#define HALF 512          // threads per row
#define EPT  4            // elements per thread
#define NW   (NT / 64)

typedef unsigned long long u64;
typedef unsigned int       u32;

__device__ inline u32 f2key(float f) {
    u32 u = __float_as_uint(f);
    return (u & 0x80000000u) ? ~u : (u | 0x80000000u);
}
__device__ inline float key2f(u32 u) {
    u = (u & 0x80000000u) ? (u & 0x7fffffffu) : ~u;
    return __uint_as_float(u);
}

__device__ inline double wave_red(double v) {
#pragma unroll
    for (int o = 32; o > 0; o >>= 1) v += __shfl_down(v, o, 64);
    return v;
}

// One block per batch row. Threads [0,512) soft-rank the pred row, [512,1024)
// the target row, concurrently. Then all threads do the Pearson correlation.
__global__ __launch_bounds__(NT) void spearman_rank_kernel(
        const float* __restrict__ pred, const float* __restrict__ target,
        float* __restrict__ ws) {
    __shared__ u64    kk[2][N];      // sort exchange buffer (32 KB)
    __shared__ double bsum[2][N];    // PAVA block sums (32 KB); aliased float* means
    __shared__ int    bcnt[2][N];    // PAVA block counts -> block starts (16 KB)
    __shared__ int    nb[2][HALF];   // per-chunk block-list lengths
    __shared__ int    nf_sh[2];
    __shared__ float  rankv[2][N];   // rank vectors (16 KB)
    __shared__ double redA[NW], redB[NW], redC[NW];
    __shared__ double mshare[2];

    const int tid = threadIdx.x;
    const int r   = tid >> 9;            // 0 = pred, 1 = target
    const int t   = tid & (HALF - 1);    // local thread within row
    const int b   = blockIdx.x;

    const float* row = (r == 0 ? pred : target) + (size_t)b * N;

    // ---- load 4 consecutive elements, pack (sortable key | original index)
    u64 key[EPT];
    {
        const float4 v = *(const float4*)(row + t * 4);
        const float f[4] = {v.x, v.y, v.z, v.w};
#pragma unroll
        for (int e = 0; e < EPT; ++e) {
            const int g = t * 4 + e;
            key[e] = ((u64)f2key(f[e]) << 32) | (u32)g;
        }
    }

    // ---- bitonic sort, descending on u64 (keys unique -> exact comparators)
    // element index g = t*4+e. j=1,2: in-thread. j=4..128: shfl_xor (d=j/4).
    // j=256,512,1024: LDS exchange.
    for (int k = 2; k <= N; k <<= 1) {
        for (int j = k >> 1; j > 0; j >>= 1) {
            if (j >= 256) {
                __syncthreads();   // protect WAR vs previous LDS pass reads
#pragma unroll
                for (int e = 0; e < EPT; ++e) kk[r][t * 4 + e] = key[e];
                __syncthreads();
#pragma unroll
                for (int e = 0; e < EPT; ++e) {
                    const int g = t * 4 + e;
                    const u64 p = kk[r][g ^ j];
                    const bool keep_max = (((g & k) == 0) == ((g & j) == 0));
                    key[e] = keep_max ? (key[e] > p ? key[e] : p)
                                      : (key[e] < p ? key[e] : p);
                }
            } else if (j >= 4) {
                const int d = j >> 2;
#pragma unroll
                for (int e = 0; e < EPT; ++e) {
                    const int g = t * 4 + e;
                    const u64 p = __shfl_xor(key[e], d, 64);
                    const bool keep_max = (((g & k) == 0) == ((g & j) == 0));
                    key[e] = keep_max ? (key[e] > p ? key[e] : p)
                                      : (key[e] < p ? key[e] : p);
                }
            } else if (j == 2) {
#pragma unroll
                for (int e0 = 0; e0 < 2; ++e0) {   // pairs (0,2),(1,3)
                    const int e1 = e0 + 2;
                    const int g  = t * 4 + e0;
                    const bool dir = ((g & k) == 0);
                    const u64 a = key[e0], c = key[e1];
                    if (dir ? (a < c) : (a > c)) { key[e0] = c; key[e1] = a; }
                }
            } else {
#pragma unroll
                for (int e0 = 0; e0 < 4; e0 += 2) { // pairs (0,1),(2,3)
                    const int e1 = e0 + 1;
                    const int g  = t * 4 + e0;
                    const bool dir = ((g & k) == 0);
                    const u64 a = key[e0], c = key[e1];
                    if (dir ? (a < c) : (a > c)) { key[e0] = c; key[e1] = a; }
                }
            }
        }
    }

    // ---- phase 1: PAVA (non-increasing) on own 4 sorted elements.
    // y[g] = s[g] - (N - g)
    {
        const int base = t * 4;
        int m = 0;
#pragma unroll
        for (int e = 0; e < EPT; ++e) {
            const int g = base + e;
            double s = (double)key2f((u32)(key[e] >> 32)) - (double)(N - g);
            int q = 1;
            while (m > 0) {
                const double ps = bsum[r][base + m - 1];
                const int    pq = bcnt[r][base + m - 1];
                if (ps * (double)q < s * (double)pq) { s += ps; q += pq; --m; }
                else break;
            }
            bsum[r][base + m] = s; bcnt[r][base + m] = q; ++m;
        }
        nb[r][t] = m;
    }

    // ---- phase 2: parallel tree merge (9 levels), both rows concurrently
    for (int l = 0; l < 9; ++l) {
        __syncthreads();
        const int pairs = HALF >> (l + 1);
        if (t < pairs) {
            const int W  = 1 << l;
            const int c  = t << (l + 1);
            const int lb = c * 4;
            const int rb = (c + W) * 4;
            int m = nb[r][c];
            const int rn = nb[r][c + W];
            for (int x = 0; x < rn; ++x) {
                double s = bsum[r][rb + x]; int q = bcnt[r][rb + x];
                while (m > 0) {
                    const double ps = bsum[r][lb + m - 1];
                    const int    pq = bcnt[r][lb + m - 1];
                    if (ps * (double)q < s * (double)pq) { s += ps; q += pq; --m; }
                    else break;
                }
                bsum[r][lb + m] = s; bcnt[r][lb + m] = q; ++m;
            }
            nb[r][c] = m;
        }
    }
    __syncthreads();

    // ---- compact: bcnt -> block starts, low floats of bsum -> means
    if (t == 0) {
        const int m = nb[r][0];
        float* bmean = (float*)&bsum[r][0];
        int st = 0;
        for (int f = 0; f < m; ++f) {
            const int    c = bcnt[r][f];
            const double s = bsum[r][f];
            bcnt[r][f] = st;
            bmean[f]   = (float)(s / (double)c);
            st += c;
        }
        nf_sh[r] = m;
    }
    __syncthreads();

    // ---- phase 3: expand means (binary search) and scatter ranks
    {
        const int m = nf_sh[r];
        const float* bmean  = (const float*)&bsum[r][0];
        const int*   bstart = &bcnt[r][0];
#pragma unroll
        for (int e = 0; e < EPT; ++e) {
            const int i = t * 4 + e;
            int lo = 0, hi = m - 1;
            while (lo < hi) {
                const int mid = (lo + hi + 1) >> 1;
                if (bstart[mid] <= i) lo = mid; else hi = mid - 1;
            }
            const float val = key2f((u32)(key[e] >> 32));
            const int   idx = (int)(key[e] & 0xffffffffu);
            rankv[r][idx] = val - bmean[lo];
        }
    }
    __syncthreads();

    // ---- Pearson correlation (two-pass, double accumulators)
    double sp = 0.0, st2 = 0.0;
    for (int i = tid; i < N; i += NT) {
        sp  += (double)rankv[0][i];
        st2 += (double)rankv[1][i];
    }
    sp = wave_red(sp); st2 = wave_red(st2);
    const int w = tid >> 6, lane = tid & 63;
    if (lane == 0) { redA[w] = sp; redB[w] = st2; }
    __syncthreads();
    if (tid == 0) {
        double a = 0.0, c = 0.0;
        for (int i = 0; i < NW; ++i) { a += redA[i]; c += redB[i]; }
        mshare[0] = a / (double)N;
        mshare[1] = c / (double)N;
    }
    __syncthreads();
    const double mp = mshare[0], mt = mshare[1];
    double cv = 0.0, vp = 0.0, vt = 0.0;
    for (int i = tid; i < N; i += NT) {
        const double a = (double)rankv[0][i] - mp;
        const double c = (double)rankv[1][i] - mt;
        cv += a * c; vp += a * a; vt += c * c;
    }
    cv = wave_red(cv); vp = wave_red(vp); vt = wave_red(vt);
    if (lane == 0) { redA[w] = cv; redB[w] = vp; redC[w] = vt; }
    __syncthreads();
    if (tid == 0) {
        double cvs = 0.0, vps = 0.0, vts = 0.0;
        for (int i = 0; i < NW; ++i) { cvs += redA[i]; vps += redB[i]; vts += redC[i]; }
        ws[b] = (float)(cvs / (sqrt(vps) * sqrt(vts) + 1e-8));
    }
}

__global__ void spearman_finalize(const float* __restrict__ ws,
                                  float* __restrict__ out, int B) {
    if (threadIdx.x == 0 && blockIdx.x == 0) {
        float s = 0.f;
        for (int i = 0; i < B; ++i) s += ws[i];
        out[0] = 1.0f - s / (float)B;
    }
}

extern "C" void kernel_launch(void* const* d_in, const int* in_sizes, int n_in,
                              void* d_out, int out_size, void* d_ws, size_t ws_size,
                              hipStream_t stream) {
    const float* pred   = (const float*)d_in[0];
    const float* target = (const float*)d_in[1];
    float* out = (float*)d_out;
    float* ws  = (float*)d_ws;
    const int B = in_sizes[0] / N;   // 8

    spearman_rank_kernel<<<B, NT, 0, stream>>>(pred, target, ws);
    spearman_finalize<<<1, 64, 0, stream>>>(ws, out, B);
}

// Round 4
// 34.406 us; speedup vs baseline: 7.4617x; 1.3667x over previous
//
#include <hip/hip_runtime.h>
#include <math.h>

#define N    2048
#define NT1  512          // threads per rank block (one row per block)
#define EPT  4            // elements per thread
#define NROW 16           // 2 * B rows

typedef unsigned int u32;

__device__ inline u32 f2key(float f) {
    u32 u = __float_as_uint(f);
    return (u & 0x80000000u) ? ~u : (u | 0x80000000u);
}
__device__ inline float key2f(u32 u) {
    u = (u & 0x80000000u) ? (u & 0x7fffffffu) : ~u;
    return __uint_as_float(u);
}

__device__ inline double wave_red(double v) {
#pragma unroll
    for (int o = 32; o > 0; o >>= 1) v += __shfl_down(v, o, 64);
    return v;
}

// One block per row (16 rows = 8 pred + 8 target). Sorts u32 keys (descending),
// exact PAVA via parallel tree merge, recovers positions by binary search,
// writes the rank vector to ranks[row][2048] in global scratch.
__global__ __launch_bounds__(NT1) void rank_kernel(
        const float* __restrict__ pred, const float* __restrict__ target,
        float* __restrict__ ranks) {
    __shared__ u32    kk[N];       // sort exchange buffer / final sorted keys
    __shared__ double bsum[N];     // PAVA block sums; later aliased float* means
    __shared__ int    bcnt[N];     // PAVA block counts -> block starts
    __shared__ int    nb[NT1];     // per-chunk block-list lengths
    __shared__ int    nf_sh;

    const int t  = threadIdx.x;
    const int rr = blockIdx.x;     // 0..7 pred rows, 8..15 target rows
    const float* row = (rr < 8) ? (pred + (size_t)rr * N)
                                : (target + (size_t)(rr - 8) * N);

    // ---- load 4 consecutive floats; keep original keys in registers
    const float4 v = *(const float4*)(row + t * 4);
    u32 ok[EPT] = {f2key(v.x), f2key(v.y), f2key(v.z), f2key(v.w)};
    u32 key[EPT] = {ok[0], ok[1], ok[2], ok[3]};

    // ---- bitonic sort, descending, u32 keys only.
    // g = t*4+e. j=1,2: in-thread. j=4..128: shfl_xor (d=j/4). j>=256: LDS.
    for (int k = 2; k <= N; k <<= 1) {
        for (int j = k >> 1; j > 0; j >>= 1) {
            if (j >= 256) {
                __syncthreads();   // WAR vs previous LDS-pass reads
#pragma unroll
                for (int e = 0; e < EPT; ++e) kk[t * 4 + e] = key[e];
                __syncthreads();
#pragma unroll
                for (int e = 0; e < EPT; ++e) {
                    const int g = t * 4 + e;
                    const u32 p = kk[g ^ j];
                    const bool keep_max = (((g & k) == 0) == ((g & j) == 0));
                    key[e] = keep_max ? (key[e] > p ? key[e] : p)
                                      : (key[e] < p ? key[e] : p);
                }
            } else if (j >= 4) {
                const int d = j >> 2;
#pragma unroll
                for (int e = 0; e < EPT; ++e) {
                    const int g = t * 4 + e;
                    const u32 p = (u32)__shfl_xor((int)key[e], d, 64);
                    const bool keep_max = (((g & k) == 0) == ((g & j) == 0));
                    key[e] = keep_max ? (key[e] > p ? key[e] : p)
                                      : (key[e] < p ? key[e] : p);
                }
            } else if (j == 2) {
#pragma unroll
                for (int e0 = 0; e0 < 2; ++e0) {     // pairs (0,2),(1,3)
                    const int e1 = e0 + 2;
                    const int g  = t * 4 + e0;
                    const bool dir = ((g & k) == 0);
                    const u32 a = key[e0], c = key[e1];
                    if (dir ? (a < c) : (a > c)) { key[e0] = c; key[e1] = a; }
                }
            } else {
#pragma unroll
                for (int e0 = 0; e0 < 4; e0 += 2) {  // pairs (0,1),(2,3)
                    const int e1 = e0 + 1;
                    const int g  = t * 4 + e0;
                    const bool dir = ((g & k) == 0);
                    const u32 a = key[e0], c = key[e1];
                    if (dir ? (a < c) : (a > c)) { key[e0] = c; key[e1] = a; }
                }
            }
        }
    }

    // ---- publish sorted keys for the binary search
    __syncthreads();               // last LDS-stage reads done
#pragma unroll
    for (int e = 0; e < EPT; ++e) kk[t * 4 + e] = key[e];

    // ---- phase 1: PAVA (non-increasing) on own 4 sorted elements.
    // y[g] = s[g] - (N - g); sums kept exactly in double.
    {
        const int base = t * 4;
        int m = 0;
#pragma unroll
        for (int e = 0; e < EPT; ++e) {
            const int g = base + e;
            double s = (double)key2f(key[e]) - (double)(N - g);
            int q = 1;
            while (m > 0) {
                const double ps = bsum[base + m - 1];
                const int    pq = bcnt[base + m - 1];
                if (ps * (double)q < s * (double)pq) { s += ps; q += pq; --m; }
                else break;
            }
            bsum[base + m] = s; bcnt[base + m] = q; ++m;
        }
        nb[t] = m;
    }

    // ---- phase 2: parallel tree merge (9 levels)
    for (int l = 0; l < 9; ++l) {
        __syncthreads();
        const int pairs = NT1 >> (l + 1);
        if (t < pairs) {
            const int W  = 1 << l;
            const int c  = t << (l + 1);
            const int lb = c * 4;
            const int rb = (c + W) * 4;
            int m = nb[c];
            const int rn = nb[c + W];
            for (int x = 0; x < rn; ++x) {
                double s = bsum[rb + x]; int q = bcnt[rb + x];
                while (m > 0) {
                    const double ps = bsum[lb + m - 1];
                    const int    pq = bcnt[lb + m - 1];
                    if (ps * (double)q < s * (double)pq) { s += ps; q += pq; --m; }
                    else break;
                }
                bsum[lb + m] = s; bcnt[lb + m] = q; ++m;
            }
            nb[c] = m;
        }
    }
    __syncthreads();

    // ---- compact: bcnt -> block starts, low floats of bsum -> means
    if (t == 0) {
        const int m = nb[0];
        float* bmean = (float*)bsum;
        int st = 0;
        for (int f = 0; f < m; ++f) {
            const int    c = bcnt[f];
            const double s = bsum[f];
            bcnt[f] = st;
            bmean[f] = (float)(s / (double)c);
            st += c;
        }
        nf_sh = m;
    }
    __syncthreads();

    // ---- phase 3: find each original element's sorted position (leftmost
    // equal key -> ties provably land in the same PAVA block, so exact),
    // then rank = value - blockmean; coalesced float4 store.
    {
        const int m = nf_sh;
        const float* bmean  = (const float*)bsum;
        float o4[EPT];
#pragma unroll
        for (int e = 0; e < EPT; ++e) {
            const u32 myk = ok[e];
            int lo = 0, hi = N - 1;
            while (lo < hi) {                 // first i with kk[i] <= myk
                const int mid = (lo + hi) >> 1;
                if (kk[mid] > myk) lo = mid + 1; else hi = mid;
            }
            int blo = 0, bhi = m - 1;
            while (blo < bhi) {               // last f with bstart[f] <= lo
                const int bm = (blo + bhi + 1) >> 1;
                if (bcnt[bm] <= lo) blo = bm; else bhi = bm - 1;
            }
            o4[e] = key2f(myk) - bmean[blo];
        }
        float4 out4 = {o4[0], o4[1], o4[2], o4[3]};
        *(float4*)(ranks + (size_t)rr * N + t * 4) = out4;
    }
}

// One block, one wave per batch: Pearson correlation of rank rows b and b+8,
// then 1 - mean over batches.
__global__ __launch_bounds__(512) void corr_finalize_kernel(
        const float* __restrict__ ranks, float* __restrict__ out, int B) {
    __shared__ double sh[8];
    const int w = threadIdx.x >> 6, lane = threadIdx.x & 63;

    if (w < B) {
        const float* rp = ranks + (size_t)w * N;
        const float* rt = ranks + (size_t)(w + B) * N;
        double sp = 0, st = 0, spp = 0, stt = 0, spt = 0;
        for (int i = lane; i < N / 4; i += 64) {
            const float4 a = ((const float4*)rp)[i];
            const float4 c = ((const float4*)rt)[i];
            const double ax = a.x, ay = a.y, az = a.z, aw = a.w;
            const double cx = c.x, cy = c.y, cz = c.z, cw = c.w;
            sp  += ax + ay + az + aw;
            st  += cx + cy + cz + cw;
            spp += ax * ax + ay * ay + az * az + aw * aw;
            stt += cx * cx + cy * cy + cz * cz + cw * cw;
            spt += ax * cx + ay * cy + az * cz + aw * cw;
        }
        sp  = wave_red(sp);  st  = wave_red(st);
        spp = wave_red(spp); stt = wave_red(stt); spt = wave_red(spt);
        if (lane == 0) {
            const double n  = (double)N;
            const double cv = spt - sp * st / n;
            const double vp = spp - sp * sp / n;
            const double vt = stt - st * st / n;
            sh[w] = cv / (sqrt(vp) * sqrt(vt) + 1e-8);
        }
    }
    __syncthreads();
    if (threadIdx.x == 0) {
        double s = 0.0;
        for (int i = 0; i < B; ++i) s += sh[i];
        out[0] = (float)(1.0 - s / (double)B);
    }
}

extern "C" void kernel_launch(void* const* d_in, const int* in_sizes, int n_in,
                              void* d_out, int out_size, void* d_ws, size_t ws_size,
                              hipStream_t stream) {
    const float* pred   = (const float*)d_in[0];
    const float* target = (const float*)d_in[1];
    float* out   = (float*)d_out;
    float* ranks = (float*)d_ws;            // 16 * 2048 * 4 = 128 KB
    const int B = in_sizes[0] / N;          // 8

    rank_kernel<<<2 * B, NT1, 0, stream>>>(pred, target, ranks);
    corr_finalize_kernel<<<1, 512, 0, stream>>>(ranks, out, B);
}

// Round 5
// 32.291 us; speedup vs baseline: 7.9506x; 1.0655x over previous
//
#include <hip/hip_runtime.h>
#include <math.h>

#define N      2048
#define B      8
#define NROW   (2 * B)       // 16 rows: 8 pred + 8 target
#define CHUNKS 16
#define EPB    (N / CHUNKS)  // 128 elements ranked per K1 block
#define K1T    512
#define K2T    512

typedef unsigned long long u64;
typedef unsigned int       u32;

// ws layout (4-byte units):
//   sv     float [NROW][N]   @ 0
//   pos    int   [NROW][N]   @ NROW*N
//   bmean  float [NROW][N]   @ 2*NROW*N
//   bstart int   [NROW][N]   @ 3*NROW*N
//   marr   int   [NROW]      @ 4*NROW*N
//   cnt    int               @ 4*NROW*N + NROW
#define WS_SV     0
#define WS_POS    (NROW * N)
#define WS_BMEAN  (2 * NROW * N)
#define WS_BSTART (3 * NROW * N)
#define WS_MARR   (4 * NROW * N)
#define WS_CNT    (4 * NROW * N + NROW)

__device__ inline u32 f2key(float f) {
    u32 u = __float_as_uint(f);
    return (u & 0x80000000u) ? ~u : (u | 0x80000000u);
}
__device__ inline float key2f(u32 u) {
    u = (u & 0x80000000u) ? (u & 0x7fffffffu) : ~u;
    return __uint_as_float(u);
}

__device__ inline double wave_red(double v) {
#pragma unroll
    for (int o = 32; o > 0; o >>= 1) v += __shfl_down(v, o, 64);
    return v;
}

// K1: counting-rank. Block = (row, chunk of 128 elements). Stages the row's
// u64 keys (value<<32 | index: total order, tie-exact) in LDS; 4 threads per
// element each count "greater" over one quarter (uniform broadcast reads).
// Writes pos[row][i] and scatters sorted values sv[row][pos]=v. Also resets
// the K2 completion counter (block 0) so every replay starts identically.
__global__ __launch_bounds__(K1T) void count_rank_kernel(
        const float* __restrict__ pred, const float* __restrict__ target,
        float* __restrict__ ws) {
    __shared__ u64 keys[N];
    __shared__ u32 scnt[K1T];

    const int t  = threadIdx.x;
    const int rr = blockIdx.x >> 4;    // row 0..15
    const int ch = blockIdx.x & 15;    // chunk 0..15
    const float* row = (rr < B) ? pred + (size_t)rr * N
                                : target + (size_t)(rr - B) * N;
    float* sv  = ws + WS_SV;
    int*   pos = (int*)ws + WS_POS;

    if (blockIdx.x == 0 && t == 0) ((int*)ws)[WS_CNT] = 0;

    {   // stage keys: 4 consecutive elements per thread
        const float4 v = *(const float4*)(row + t * 4);
        const int g = t * 4;
        keys[g + 0] = ((u64)f2key(v.x) << 32) | (u32)(g + 0);
        keys[g + 1] = ((u64)f2key(v.y) << 32) | (u32)(g + 1);
        keys[g + 2] = ((u64)f2key(v.z) << 32) | (u32)(g + 2);
        keys[g + 3] = ((u64)f2key(v.w) << 32) | (u32)(g + 3);
    }
    __syncthreads();

    const int e  = t & (EPB - 1);      // element within chunk
    const int h  = t >> 7;             // quarter 0..3
    const int gi = ch * EPB + e;
    const u64 Ki = keys[gi];
    u32 cnt = 0;
    const int j0 = h * (N / 4);
#pragma unroll 8
    for (int j = j0; j < j0 + N / 4; ++j)
        cnt += (keys[j] > Ki) ? 1u : 0u;
    scnt[t] = cnt;
    __syncthreads();

    if (t < EPB) {
        const u32 p = scnt[t] + scnt[t + 128] + scnt[t + 256] + scnt[t + 384];
        pos[rr * N + gi] = (int)p;
        sv[rr * N + (int)p] = key2f((u32)(Ki >> 32));   // descending sorted
    }
}

// K2: one block per row: exact PAVA (local 4-elem PAVA + 9-level tree merge,
// double sums), publish block means/starts/m to ws. The last block to finish
// (threadfence + device atomicAdd ticket) computes the 8 Pearson correlations
// of the rank vectors (ranks derived on the fly: v - bmean[block(pos)]) and
// writes 1 - mean(spearman).
__global__ __launch_bounds__(K2T) void pava_corr_kernel(
        const float* __restrict__ pred, const float* __restrict__ target,
        float* __restrict__ out, float* __restrict__ ws) {
    __shared__ double bsum[N];     // block sums; later aliased float* means
    __shared__ int    bcnt[N];     // block counts -> block starts
    __shared__ int    nb[K2T];
    __shared__ int    nf_sh;
    __shared__ int    lastFlag;
    __shared__ double sh[B];

    const int t  = threadIdx.x;
    const int rr = blockIdx.x;
    float* sv     = ws + WS_SV;
    int*   pos    = (int*)ws + WS_POS;
    float* bmean  = ws + WS_BMEAN;
    int*   bstart = (int*)ws + WS_BSTART;
    int*   marr   = (int*)ws + WS_MARR;
    int*   cntp   = (int*)ws + WS_CNT;

    // phase 1: local PAVA (non-increasing) on own 4 sorted elements.
    // y[g] = s[g] - (N - g); all sums exact-enough in double.
    {
        const float4 s4 = *(const float4*)(sv + (size_t)rr * N + t * 4);
        const float sarr[4] = {s4.x, s4.y, s4.z, s4.w};
        const int base = t * 4;
        int m = 0;
#pragma unroll
        for (int e = 0; e < 4; ++e) {
            const int g = base + e;
            double s = (double)sarr[e] - (double)(N - g);
            int q = 1;
            while (m > 0) {
                const double ps = bsum[base + m - 1];
                const int    pq = bcnt[base + m - 1];
                if (ps * (double)q < s * (double)pq) { s += ps; q += pq; --m; }
                else break;
            }
            bsum[base + m] = s; bcnt[base + m] = q; ++m;
        }
        nb[t] = m;
    }

    // phase 2: parallel tree merge (9 levels)
    for (int l = 0; l < 9; ++l) {
        __syncthreads();
        const int pairs = K2T >> (l + 1);
        if (t < pairs) {
            const int W  = 1 << l;
            const int c  = t << (l + 1);
            const int lb = c * 4;
            const int rb = (c + W) * 4;
            int m = nb[c];
            const int rn = nb[c + W];
            for (int x = 0; x < rn; ++x) {
                double s = bsum[rb + x]; int q = bcnt[rb + x];
                while (m > 0) {
                    const double ps = bsum[lb + m - 1];
                    const int    pq = bcnt[lb + m - 1];
                    if (ps * (double)q < s * (double)pq) { s += ps; q += pq; --m; }
                    else break;
                }
                bsum[lb + m] = s; bcnt[lb + m] = q; ++m;
            }
            nb[c] = m;
        }
    }
    __syncthreads();

    // compact: bcnt -> starts, low floats of bsum -> means
    if (t == 0) {
        const int m = nb[0];
        float* bm = (float*)bsum;
        int st = 0;
        for (int f = 0; f < m; ++f) {
            const int    c = bcnt[f];
            const double s = bsum[f];
            bcnt[f] = st;
            bm[f]   = (float)(s / (double)c);
            st += c;
        }
        nf_sh = m;
    }
    __syncthreads();

    // publish to ws (coalesced)
    {
        const int m = nf_sh;
        const float* bm = (const float*)bsum;
        for (int f = t; f < m; f += K2T) {
            bmean[(size_t)rr * N + f]  = bm[f];
            bstart[(size_t)rr * N + f] = bcnt[f];
        }
        if (t == 0) marr[rr] = m;
    }

    // completion ticket: last block does the correlation
    __threadfence();
    __syncthreads();
    if (t == 0) {
        const int old = atomicAdd(cntp, 1);
        lastFlag = (old == NROW - 1);
    }
    __syncthreads();
    if (!lastFlag) return;
    __threadfence();   // acquire: see peers' bmean/bstart/marr

    // wave w = batch w (8 waves). rank_i = v_i - bmean[block containing pos_i]
    const int w = t >> 6, lane = t & 63;
    const float* vp = pred   + (size_t)w * N;
    const float* vt = target + (size_t)w * N;
    const int* pp = pos + (size_t)w * N;
    const int* pt = pos + (size_t)(w + B) * N;
    const float* bmp = bmean  + (size_t)w * N;
    const int*   bsp = bstart + (size_t)w * N;
    const float* bmt = bmean  + (size_t)(w + B) * N;
    const int*   bst = bstart + (size_t)(w + B) * N;
    const int mp = marr[w], mt = marr[w + B];

    double sp = 0, st = 0, spp = 0, stt = 0, spt = 0;
    for (int i = lane; i < N; i += 64) {
        const float a = vp[i], c = vt[i];
        int ppos = pp[i], lo = 0, hi = mp - 1;
        while (lo < hi) { const int mid = (lo + hi + 1) >> 1;
                          if (bsp[mid] <= ppos) lo = mid; else hi = mid - 1; }
        const float ra = a - bmp[lo];
        int tpos = pt[i]; lo = 0; hi = mt - 1;
        while (lo < hi) { const int mid = (lo + hi + 1) >> 1;
                          if (bst[mid] <= tpos) lo = mid; else hi = mid - 1; }
        const float rc = c - bmt[lo];
        const double da = ra, dc = rc;
        sp += da; st += dc; spp += da * da; stt += dc * dc; spt += da * dc;
    }
    sp  = wave_red(sp);  st  = wave_red(st);
    spp = wave_red(spp); stt = wave_red(stt); spt = wave_red(spt);
    if (lane == 0) {
        const double n  = (double)N;
        const double cv  = spt - sp * st / n;
        const double vp2 = spp - sp * sp / n;
        const double vt2 = stt - st * st / n;
        sh[w] = cv / (sqrt(vp2) * sqrt(vt2) + 1e-8);
    }
    __syncthreads();
    if (t == 0) {
        double s = 0.0;
        for (int i = 0; i < B; ++i) s += sh[i];
        out[0] = (float)(1.0 - s / (double)B);
    }
}

extern "C" void kernel_launch(void* const* d_in, const int* in_sizes, int n_in,
                              void* d_out, int out_size, void* d_ws, size_t ws_size,
                              hipStream_t stream) {
    const float* pred   = (const float*)d_in[0];
    const float* target = (const float*)d_in[1];
    float* out = (float*)d_out;
    float* ws  = (float*)d_ws;

    count_rank_kernel<<<NROW * CHUNKS, K1T, 0, stream>>>(pred, target, ws);
    pava_corr_kernel<<<NROW, K2T, 0, stream>>>(pred, target, out, ws);
}